// Round 12
// baseline (897.222 us; speedup 1.0000x reference)
//
#include <hip/hip_runtime.h>

// GraphSAGE 3-layer encoder, bf16 feature pipeline.
// Batched CSR build (hist -> scan -> fill(src,dst pairs)), then per layer:
// gather-mean (EDGE-PARALLEL: block of 4 waves owns 16 dst rows; waves split
// the contiguous edge range, each edge = 1 coalesced row read + ds_add_f32
// into LDS accumulators; block writes bf16 mean rows) -> GEMM (MFMA bf16,
// W staged once into LDS, single barrier): out = mean@Wl + b + x@Wr, PReLU.

constexpr int cN0 = 400000, cN1 = 200000, cN2 = 100000, cN3 = 50000;
constexpr int cE1 = 500000, cE2 = 300000, cE3 = 150000;
constexpr int cNT = cN1 + cN2 + cN3;   // 350000 concatenated dst rows
constexpr int cET = cE1 + cE2 + cE3;   // 950000 concatenated edges

#define NDIV_UP(a, b) (((a) + (b) - 1) / (b))

typedef __attribute__((ext_vector_type(8))) short bf16x8;
typedef __attribute__((ext_vector_type(4))) float f32x4;
typedef __attribute__((ext_vector_type(4))) unsigned u32x4;

__device__ __forceinline__ unsigned fbits(float f) {
  return __builtin_bit_cast(unsigned, f);
}
__device__ __forceinline__ float ffrom(unsigned u) {
  return __builtin_bit_cast(float, u);
}
__device__ __forceinline__ unsigned short f2bf(float f) {  // round-to-nearest
  unsigned u = fbits(f);
  unsigned r = u + 0x7FFFu + ((u >> 16) & 1u);
  return (unsigned short)(r >> 16);
}

// Detect whether index buffers are int64 (JAX x64) or int32 — parallel, 1 wave.
__global__ void detect_idx64_kernel(const long long* __restrict__ p, int E,
                                    long long nmax, int* __restrict__ flag) {
  int t = threadIdx.x;
  int n = E < 512 ? E : 512;
  int bad = 0;
  for (int i = t; i < n; i += 64) {
    long long v = p[i];
    if (v < 0 || v >= nmax) bad = 1;
  }
  unsigned long long b = __ballot(bad);
  if (t == 0) *flag = (b == 0ull) ? 1 : 0;
}

__device__ __forceinline__ int load_idx(const void* p, int i, int flag) {
  return flag ? (int)((const long long*)p)[i] : ((const int*)p)[i];
}

// Histogram over concatenated dst space.
__global__ void hist3_kernel(const void* __restrict__ d1, const void* __restrict__ d2,
                             const void* __restrict__ d3, const int* __restrict__ flag,
                             int* __restrict__ CNT) {
  int e = blockIdx.x * 256 + threadIdx.x;
  if (e >= cET) return;
  int f = *flag;
  int d;
  if (e < cE1) d = load_idx(d1, e, f);
  else if (e < cE1 + cE2) d = cN1 + load_idx(d2, e - cE1, f);
  else d = cN1 + cN2 + load_idx(d3, e - cE1 - cE2, f);
  atomicAdd(&CNT[d], 1);
}

// ---- exclusive scan over CNT[cNT] -> OFFS[cNT], 1024 items / block ----
__global__ __launch_bounds__(256) void scan_reduce(const int* __restrict__ cnt,
                                                   int n, int* __restrict__ bsum) {
  __shared__ int s[256];
  int t = threadIdx.x;
  int base = blockIdx.x * 1024 + t * 4;
  int v = 0;
  if (base + 3 < n) {
    int4 c = *(const int4*)(cnt + base);
    v = c.x + c.y + c.z + c.w;
  } else {
    for (int i = 0; i < 4; ++i)
      if (base + i < n) v += cnt[base + i];
  }
  s[t] = v;
  __syncthreads();
  for (int off = 128; off > 0; off >>= 1) {
    if (t < off) s[t] += s[t + off];
    __syncthreads();
  }
  if (t == 0) bsum[blockIdx.x] = s[0];
}

// Parallel single-block exclusive scan over up to 512 block-sums.
__global__ __launch_bounds__(256) void scan_bsums(int* __restrict__ bsum, int nb) {
  __shared__ int s[256];
  int t = threadIdx.x;
  int v0 = (2 * t < nb) ? bsum[2 * t] : 0;
  int v1 = (2 * t + 1 < nb) ? bsum[2 * t + 1] : 0;
  int p = v0 + v1;
  s[t] = p;
  __syncthreads();
  for (int off = 1; off < 256; off <<= 1) {
    int x = (t >= off) ? s[t - off] : 0;
    __syncthreads();
    s[t] += x;
    __syncthreads();
  }
  int excl = s[t] - p;
  if (2 * t < nb) bsum[2 * t] = excl;
  if (2 * t + 1 < nb) bsum[2 * t + 1] = excl + v0;
}

__global__ __launch_bounds__(256) void scan_final(const int* __restrict__ cnt,
                                                  int n, const int* __restrict__ bsum,
                                                  int* __restrict__ offs) {
  __shared__ int s[256];
  int t = threadIdx.x;
  int base = blockIdx.x * 1024 + t * 4;
  int v0 = 0, v1 = 0, v2 = 0, v3 = 0;
  if (base + 3 < n) {
    int4 c = *(const int4*)(cnt + base);
    v0 = c.x; v1 = c.y; v2 = c.z; v3 = c.w;
  } else {
    if (base + 0 < n) v0 = cnt[base + 0];
    if (base + 1 < n) v1 = cnt[base + 1];
    if (base + 2 < n) v2 = cnt[base + 2];
  }
  int tsum = v0 + v1 + v2 + v3;
  s[t] = tsum;
  __syncthreads();
  for (int off = 1; off < 256; off <<= 1) {
    int x = (t >= off) ? s[t - off] : 0;
    __syncthreads();
    s[t] += x;
    __syncthreads();
  }
  int excl = s[t] - tsum;
  int o = bsum[blockIdx.x] + excl;
  if (base + 0 < n) offs[base + 0] = o;
  o += v0;
  if (base + 1 < n) offs[base + 1] = o;
  o += v1;
  if (base + 2 < n) offs[base + 2] = o;
  o += v2;
  if (base + 3 < n) offs[base + 3] = o;
}

// Bucket-fill (src,dst) pairs into concatenated EIDD.
__global__ void fill3_kernel(const void* __restrict__ s1, const void* __restrict__ d1,
                             const void* __restrict__ s2, const void* __restrict__ d2,
                             const void* __restrict__ s3, const void* __restrict__ d3,
                             const int* __restrict__ flag,
                             int* __restrict__ OFFS, int2* __restrict__ EIDD) {
  int e = blockIdx.x * 256 + threadIdx.x;
  if (e >= cET) return;
  int f = *flag;
  int s, d;
  if (e < cE1) {
    s = load_idx(s1, e, f);
    d = load_idx(d1, e, f);
  } else if (e < cE1 + cE2) {
    int i = e - cE1;
    s = load_idx(s2, i, f);
    d = cN1 + load_idx(d2, i, f);
  } else {
    int i = e - cE1 - cE2;
    s = load_idx(s3, i, f);
    d = cN1 + cN2 + load_idx(d3, i, f);
  }
  int pos = atomicAdd(&OFFS[d], 1);
  EIDD[pos] = make_int2(s, d);
}

// Pre-pack weights (all 3 layers) into per-lane MFMA B-fragment order, RTN
// bf16. Per layer: Wl|Wr x16384 u16 (64 KB).
// r = ks*4096 + cf*512 + l*8 + j ; k = ks*32+(l>>4)*8+j ; col = cf*16+(l&15).
__global__ void pack_w3_kernel(const float* __restrict__ Wl1, const float* __restrict__ Wr1,
                               const float* __restrict__ Wl2, const float* __restrict__ Wr2,
                               const float* __restrict__ Wl3, const float* __restrict__ Wr3,
                               unsigned short* __restrict__ wpk) {
  int idx = blockIdx.x * 256 + threadIdx.x;
  if (idx >= 3 * 16384) return;
  int L = idx >> 14;
  int r = idx & 16383;
  const float* Wl = L == 0 ? Wl1 : (L == 1 ? Wl2 : Wl3);
  const float* Wr = L == 0 ? Wr1 : (L == 1 ? Wr2 : Wr3);
  unsigned short* o = wpk + L * 32768;
  int j = r & 7, l = (r >> 3) & 63, cf = (r >> 9) & 7, ks = r >> 12;
  int k = ks * 32 + (l >> 4) * 8 + j;
  int col = cf * 16 + (l & 15);
  o[r] = f2bf(Wl[k * 128 + col]);
  o[16384 + r] = f2bf(Wr[k * 128 + col]);
}

// Gather-mean, EDGE-PARALLEL: block (4 waves) owns 16 dst rows and their
// contiguous CSR edge range; waves take edges round-robin. Per edge: one
// wave-uniform (src,dst) load, one coalesced row read (lane covers cols
// l and l+64 -> 2-way LDS aliasing = free), two fire-and-forget ds_add_f32
// into acc[16][128]. Different edges are independent -> deep MLP. Epilogue
// converts acc -> bf16 mean rows (16B stores).
template <bool SRCF32>
__global__ __launch_bounds__(256) void gather_kernel(
    const void* __restrict__ hsrc, const int* __restrict__ OFFS,
    const int2* __restrict__ EIDD, int rowoff,
    unsigned short* __restrict__ meanB, int n) {
  __shared__ float acc[16][128];
  __shared__ float ldsInv[16];
  const int tid = threadIdx.x;
  const int r0 = blockIdx.x * 16;
  const int gr0 = rowoff + r0;
  const int lastrow = min(r0 + 16, n);

#pragma unroll
  for (int i = 0; i < 8; ++i)
    ((float*)acc)[tid + i * 256] = 0.f;

  const int estart = (gr0 == 0) ? 0 : OFFS[gr0 - 1];
  const int eend = OFFS[rowoff + lastrow - 1];

  if (tid < 16) {
    float inv = 0.f;
    const int row = r0 + tid;
    if (row < n) {
      const int g = rowoff + row;
      const int s = g ? OFFS[g - 1] : 0;
      const int e = OFFS[g];
      inv = (e > s) ? 1.0f / (float)(e - s) : 0.0f;
    }
    ldsInv[tid] = inv;
  }
  __syncthreads();

  const int wv = tid >> 6;
  const int lane = tid & 63;
  for (int e = estart + wv; e < eend; e += 4) {
    const int2 sd = EIDD[e];
    const int r = sd.y - gr0;
    float v0, v1;
    if (SRCF32) {
      const float* rp = (const float*)hsrc + (size_t)sd.x * 128;
      v0 = rp[lane];
      v1 = rp[lane + 64];
    } else {
      const unsigned short* rp = (const unsigned short*)hsrc + (size_t)sd.x * 128;
      v0 = ffrom((unsigned)rp[lane] << 16);
      v1 = ffrom((unsigned)rp[lane + 64] << 16);
    }
    atomicAdd(&acc[r][lane], v0);
    atomicAdd(&acc[r][lane + 64], v1);
  }
  __syncthreads();

  // Write 16 bf16 mean rows: thread t -> row t/16, cols (t&15)*8..+7.
  const int lr = tid >> 4;
  const int row = r0 + lr;
  if (row < n) {
    const int col = (tid & 15) * 8;
    const float inv = ldsInv[lr];
    const float* ap = &acc[lr][col];
    u32x4 o;
#pragma unroll
    for (int p = 0; p < 4; ++p)
      o[p] = (unsigned)f2bf(ap[2 * p] * inv) |
             ((unsigned)f2bf(ap[2 * p + 1] * inv) << 16);
    *(u32x4*)(meanB + (size_t)row * 128 + col) = o;
  }
}

// GEMM: 4 waves/block, wave owns 32 rows (2x 16-row tiles).
// Phase 1: issue ALL A-loads (mean bf16 + x) into registers.
// Phase 2: stage the layer's full packed W (64 KB) into LDS (once).
// Phase 3: one barrier; ks/cf loop reads B via conflict-free ds_read_b128,
//          4 MFMA per (ks,cf); no further barriers or global B traffic.
// acc = mean@Wl + x@Wr, +bias, PReLU. Output may alias meanB: every read
// (A hoisted up front) precedes every epilogue store.
template <bool XF32, bool OUTF32>
__global__ __launch_bounds__(256, 2) void gemm_kernel(
    const unsigned short* __restrict__ meanB, const void* __restrict__ xsrc,
    const unsigned short* __restrict__ W,
    const float* __restrict__ bias, const float* __restrict__ alpha,
    void* __restrict__ outp, int n) {
  __shared__ __align__(16) unsigned short wlds[32768];  // 64 KB: full layer W
  const int tid = threadIdx.x;
  const int lane = tid & 63;
  const int wv = tid >> 6;
  const int rbase = blockIdx.x * 128 + wv * 32;
  const int g = lane >> 4;
  const int r16 = lane & 15;

  // Phase 1: all A loads issued first (latency hides under W staging).
  bf16x8 am[2][4], ax[2][4];
  float4 xr[2][4][2];
#pragma unroll
  for (int t = 0; t < 2; ++t) {
    const int row = rbase + t * 16 + r16;
    const bool ok = row < n;
#pragma unroll
    for (int ks = 0; ks < 4; ++ks) {
      if (ok) {
        am[t][ks] = *(const bf16x8*)(meanB + (size_t)row * 128 + ks * 32 + g * 8);
        if (XF32) {
          const float* xp = (const float*)xsrc + (size_t)row * 128 + ks * 32 + g * 8;
          xr[t][ks][0] = *(const float4*)(xp);
          xr[t][ks][1] = *(const float4*)(xp + 4);
        } else {
          ax[t][ks] = *(const bf16x8*)((const unsigned short*)xsrc +
                                       (size_t)row * 128 + ks * 32 + g * 8);
        }
      } else {
        am[t][ks] = (bf16x8)0;
        if (XF32) {
          xr[t][ks][0] = make_float4(0.f, 0.f, 0.f, 0.f);
          xr[t][ks][1] = make_float4(0.f, 0.f, 0.f, 0.f);
        } else {
          ax[t][ks] = (bf16x8)0;
        }
      }
    }
  }

  // Phase 2: stage W -> LDS (4096 float4, 256 threads x 16 iters).
  {
    const float4* Wg = (const float4*)W;
    float4* Ws = (float4*)wlds;
#pragma unroll
    for (int i = 0; i < 16; ++i)
      Ws[i * 256 + tid] = Wg[i * 256 + tid];
  }
  __syncthreads();

  if (XF32) {
#pragma unroll
    for (int t = 0; t < 2; ++t)
#pragma unroll
      for (int ks = 0; ks < 4; ++ks) {
        const float* xv = (const float*)&xr[t][ks][0];
        u32x4 w;
#pragma unroll
        for (int p = 0; p < 4; ++p)
          w[p] = (unsigned)f2bf(xv[2 * p]) | ((unsigned)f2bf(xv[2 * p + 1]) << 16);
        ax[t][ks] = __builtin_bit_cast(bf16x8, w);
      }
  }

  // Phase 3: MFMA loop, B from LDS.
  f32x4 acc[2][8] = {};
#pragma unroll
  for (int ks = 0; ks < 4; ++ks) {
    const unsigned short* wb = wlds + ks * 4096 + lane * 8;
#pragma unroll
    for (int cf = 0; cf < 8; ++cf) {
      const unsigned short* wp = wb + cf * 512;
      bf16x8 wl = *(const bf16x8*)(wp);
      bf16x8 wr = *(const bf16x8*)(wp + 16384);
#pragma unroll
      for (int t = 0; t < 2; ++t) {
        acc[t][cf] = __builtin_amdgcn_mfma_f32_16x16x32_bf16(am[t][ks], wl, acc[t][cf], 0, 0, 0);
        acc[t][cf] = __builtin_amdgcn_mfma_f32_16x16x32_bf16(ax[t][ks], wr, acc[t][cf], 0, 0, 0);
      }
    }
  }

  // Epilogue: C/D layout col = lane&15, row = (lane>>4)*4 + i (verified).
  const int ocol0 = lane & 15;
  const int orow_off = (lane >> 4) * 4;
#pragma unroll
  for (int cf = 0; cf < 8; ++cf) {
    const int ocol = cf * 16 + ocol0;
    const float b = bias[ocol];
    const float a = alpha[ocol];
#pragma unroll
    for (int t = 0; t < 2; ++t) {
      const int orb = rbase + t * 16 + orow_off;
#pragma unroll
      for (int i = 0; i < 4; ++i) {
        const int orow = orb + i;
        if (orow < n) {
          float v = acc[t][cf][i] + b;
          v = v > 0.f ? v : a * v;
          if (OUTF32) {
            ((float*)outp)[(size_t)orow * 128 + ocol] = v;
          } else {
            ((unsigned short*)outp)[(size_t)orow * 128 + ocol] = f2bf(v);
          }
        }
      }
    }
  }
}

extern "C" void kernel_launch(void* const* d_in, const int* in_sizes, int n_in,
                              void* d_out, int out_size, void* d_ws, size_t ws_size,
                              hipStream_t stream) {
  const float* x = (const float*)d_in[0];
  const void* src1 = d_in[1];
  const void* dst1 = d_in[2];
  const void* src2 = d_in[3];
  const void* dst2 = d_in[4];
  const void* src3 = d_in[5];
  const void* dst3 = d_in[6];
  const float* Wl1 = (const float*)d_in[7];
  const float* Wr1 = (const float*)d_in[8];
  const float* b1  = (const float*)d_in[9];
  const float* a1  = (const float*)d_in[10];
  const float* Wl2 = (const float*)d_in[11];
  const float* Wr2 = (const float*)d_in[12];
  const float* b2  = (const float*)d_in[13];
  const float* a2  = (const float*)d_in[14];
  const float* Wl3 = (const float*)d_in[15];
  const float* Wr3 = (const float*)d_in[16];
  const float* b3  = (const float*)d_in[17];
  const float* a3  = (const float*)d_in[18];

  // ws layout: M1 (N1*128 u16), M2 (N2*128 u16), M3 (N3*128 u16),
  //            CNT (cNT i), OFFS (cNT i), EIDD (2*cET i), bsum (1024 i),
  //            flag (64 i), wpk (3*32768 u16)
  unsigned short* M1 = (unsigned short*)d_ws;          // mean1 -> h1 (in-place)
  unsigned short* M2 = M1 + (size_t)cN1 * 128;         // mean2 -> h2 (in-place)
  unsigned short* M3 = M2 + (size_t)cN2 * 128;         // mean3
  int* CNT = (int*)(M3 + (size_t)cN3 * 128);
  int* OFFS = CNT + cNT;
  int2* EIDD = (int2*)(OFFS + cNT);
  int* bsum = (int*)(EIDD + cET);
  int* flag = bsum + 1024;
  unsigned short* wpk = (unsigned short*)(flag + 64);

  const int nb = NDIV_UP(cNT, 1024);  // 342 <= 512

  detect_idx64_kernel<<<1, 64, 0, stream>>>((const long long*)src1, cE1,
                                            (long long)cN0, flag);
  pack_w3_kernel<<<192, 256, 0, stream>>>(Wl1, Wr1, Wl2, Wr2, Wl3, Wr3, wpk);
  hipMemsetAsync(CNT, 0, (size_t)cNT * sizeof(int), stream);
  hist3_kernel<<<NDIV_UP(cET, 256), 256, 0, stream>>>(dst1, dst2, dst3, flag, CNT);
  scan_reduce<<<nb, 256, 0, stream>>>(CNT, cNT, bsum);
  scan_bsums<<<1, 256, 0, stream>>>(bsum, nb);
  scan_final<<<nb, 256, 0, stream>>>(CNT, cNT, bsum, OFFS);
  fill3_kernel<<<NDIV_UP(cET, 256), 256, 0, stream>>>(src1, dst1, src2, dst2,
                                                      src3, dst3, flag, OFFS, EIDD);

  // Layer 1: mean(x) -> M1 ; h1 = gemm(M1, x fp32) -> M1 (bf16, in-place)
  gather_kernel<true><<<NDIV_UP(cN1, 16), 256, 0, stream>>>(
      x, OFFS, EIDD, 0, M1, cN1);
  gemm_kernel<true, false><<<NDIV_UP(cN1, 128), 256, 0, stream>>>(
      M1, x, wpk, b1, a1, M1, cN1);

  // Layer 2: mean(h1) -> M2 ; h2 = gemm(M2, h1 bf16) -> M2 (bf16, in-place)
  gather_kernel<false><<<NDIV_UP(cN2, 16), 256, 0, stream>>>(
      M1, OFFS, EIDD, cN1, M2, cN2);
  gemm_kernel<false, false><<<NDIV_UP(cN2, 128), 256, 0, stream>>>(
      M2, M1, wpk + 32768, b2, a2, M2, cN2);

  // Layer 3: mean(h2) -> M3 ; out = gemm(M3, h2 bf16) -> d_out (fp32)
  gather_kernel<false><<<NDIV_UP(cN3, 16), 256, 0, stream>>>(
      M2, OFFS, EIDD, cN1 + cN2, M3, cN3);
  gemm_kernel<false, true><<<NDIV_UP(cN3, 128), 256, 0, stream>>>(
      M3, M2, wpk + 65536, b3, a3, d_out, cN3);
}

// Round 13
// 346.530 us; speedup vs baseline: 2.5892x; 2.5892x over previous
//
#include <hip/hip_runtime.h>

// GraphSAGE 3-layer encoder, bf16 feature pipeline.
// Batched CSR build (hist -> scan -> fill), then per layer: gather-mean
// (4 rows per wave over the rows' COMBINED contiguous edge range; uniform
// boundary predicates select the accumulator -- no divergence, no atomics)
// -> GEMM (MFMA bf16, W staged once into LDS, single barrier):
// out = mean@Wl + b + x@Wr, PReLU.

constexpr int cN0 = 400000, cN1 = 200000, cN2 = 100000, cN3 = 50000;
constexpr int cE1 = 500000, cE2 = 300000, cE3 = 150000;
constexpr int cNT = cN1 + cN2 + cN3;   // 350000 concatenated dst rows
constexpr int cET = cE1 + cE2 + cE3;   // 950000 concatenated edges

#define NDIV_UP(a, b) (((a) + (b) - 1) / (b))

typedef __attribute__((ext_vector_type(8))) short bf16x8;
typedef __attribute__((ext_vector_type(4))) float f32x4;
typedef __attribute__((ext_vector_type(4))) unsigned u32x4;

__device__ __forceinline__ unsigned fbits(float f) {
  return __builtin_bit_cast(unsigned, f);
}
__device__ __forceinline__ float ffrom(unsigned u) {
  return __builtin_bit_cast(float, u);
}
__device__ __forceinline__ unsigned short f2bf(float f) {  // round-to-nearest
  unsigned u = fbits(f);
  unsigned r = u + 0x7FFFu + ((u >> 16) & 1u);
  return (unsigned short)(r >> 16);
}

// Detect whether index buffers are int64 (JAX x64) or int32 — parallel, 1 wave.
__global__ void detect_idx64_kernel(const long long* __restrict__ p, int E,
                                    long long nmax, int* __restrict__ flag) {
  int t = threadIdx.x;
  int n = E < 512 ? E : 512;
  int bad = 0;
  for (int i = t; i < n; i += 64) {
    long long v = p[i];
    if (v < 0 || v >= nmax) bad = 1;
  }
  unsigned long long b = __ballot(bad);
  if (t == 0) *flag = (b == 0ull) ? 1 : 0;
}

__device__ __forceinline__ int load_idx(const void* p, int i, int flag) {
  return flag ? (int)((const long long*)p)[i] : ((const int*)p)[i];
}

// Histogram over concatenated dst space.
__global__ void hist3_kernel(const void* __restrict__ d1, const void* __restrict__ d2,
                             const void* __restrict__ d3, const int* __restrict__ flag,
                             int* __restrict__ CNT) {
  int e = blockIdx.x * 256 + threadIdx.x;
  if (e >= cET) return;
  int f = *flag;
  int d;
  if (e < cE1) d = load_idx(d1, e, f);
  else if (e < cE1 + cE2) d = cN1 + load_idx(d2, e - cE1, f);
  else d = cN1 + cN2 + load_idx(d3, e - cE1 - cE2, f);
  atomicAdd(&CNT[d], 1);
}

// ---- exclusive scan over CNT[cNT] -> OFFS[cNT], 1024 items / block ----
__global__ __launch_bounds__(256) void scan_reduce(const int* __restrict__ cnt,
                                                   int n, int* __restrict__ bsum) {
  __shared__ int s[256];
  int t = threadIdx.x;
  int base = blockIdx.x * 1024 + t * 4;
  int v = 0;
  if (base + 3 < n) {
    int4 c = *(const int4*)(cnt + base);
    v = c.x + c.y + c.z + c.w;
  } else {
    for (int i = 0; i < 4; ++i)
      if (base + i < n) v += cnt[base + i];
  }
  s[t] = v;
  __syncthreads();
  for (int off = 128; off > 0; off >>= 1) {
    if (t < off) s[t] += s[t + off];
    __syncthreads();
  }
  if (t == 0) bsum[blockIdx.x] = s[0];
}

// Parallel single-block exclusive scan over up to 512 block-sums.
__global__ __launch_bounds__(256) void scan_bsums(int* __restrict__ bsum, int nb) {
  __shared__ int s[256];
  int t = threadIdx.x;
  int v0 = (2 * t < nb) ? bsum[2 * t] : 0;
  int v1 = (2 * t + 1 < nb) ? bsum[2 * t + 1] : 0;
  int p = v0 + v1;
  s[t] = p;
  __syncthreads();
  for (int off = 1; off < 256; off <<= 1) {
    int x = (t >= off) ? s[t - off] : 0;
    __syncthreads();
    s[t] += x;
    __syncthreads();
  }
  int excl = s[t] - p;
  if (2 * t < nb) bsum[2 * t] = excl;
  if (2 * t + 1 < nb) bsum[2 * t + 1] = excl + v0;
}

__global__ __launch_bounds__(256) void scan_final(const int* __restrict__ cnt,
                                                  int n, const int* __restrict__ bsum,
                                                  int* __restrict__ offs) {
  __shared__ int s[256];
  int t = threadIdx.x;
  int base = blockIdx.x * 1024 + t * 4;
  int v0 = 0, v1 = 0, v2 = 0, v3 = 0;
  if (base + 3 < n) {
    int4 c = *(const int4*)(cnt + base);
    v0 = c.x; v1 = c.y; v2 = c.z; v3 = c.w;
  } else {
    if (base + 0 < n) v0 = cnt[base + 0];
    if (base + 1 < n) v1 = cnt[base + 1];
    if (base + 2 < n) v2 = cnt[base + 2];
  }
  int tsum = v0 + v1 + v2 + v3;
  s[t] = tsum;
  __syncthreads();
  for (int off = 1; off < 256; off <<= 1) {
    int x = (t >= off) ? s[t - off] : 0;
    __syncthreads();
    s[t] += x;
    __syncthreads();
  }
  int excl = s[t] - tsum;
  int o = bsum[blockIdx.x] + excl;
  if (base + 0 < n) offs[base + 0] = o;
  o += v0;
  if (base + 1 < n) offs[base + 1] = o;
  o += v1;
  if (base + 2 < n) offs[base + 2] = o;
  o += v2;
  if (base + 3 < n) offs[base + 3] = o;
}

// Bucket-fill into concatenated EID; post-fill OFFS[d] == pre-fill OFFS[d+1].
__global__ void fill3_kernel(const void* __restrict__ s1, const void* __restrict__ d1,
                             const void* __restrict__ s2, const void* __restrict__ d2,
                             const void* __restrict__ s3, const void* __restrict__ d3,
                             const int* __restrict__ flag,
                             int* __restrict__ OFFS, int* __restrict__ EID) {
  int e = blockIdx.x * 256 + threadIdx.x;
  if (e >= cET) return;
  int f = *flag;
  int s, d;
  if (e < cE1) {
    s = load_idx(s1, e, f);
    d = load_idx(d1, e, f);
  } else if (e < cE1 + cE2) {
    int i = e - cE1;
    s = load_idx(s2, i, f);
    d = cN1 + load_idx(d2, i, f);
  } else {
    int i = e - cE1 - cE2;
    s = load_idx(s3, i, f);
    d = cN1 + cN2 + load_idx(d3, i, f);
  }
  int pos = atomicAdd(&OFFS[d], 1);
  EID[pos] = s;
}

// Pre-pack weights (all 3 layers) into per-lane MFMA B-fragment order, RTN
// bf16. Per layer: Wl|Wr x16384 u16 (64 KB).
// r = ks*4096 + cf*512 + l*8 + j ; k = ks*32+(l>>4)*8+j ; col = cf*16+(l&15).
__global__ void pack_w3_kernel(const float* __restrict__ Wl1, const float* __restrict__ Wr1,
                               const float* __restrict__ Wl2, const float* __restrict__ Wr2,
                               const float* __restrict__ Wl3, const float* __restrict__ Wr3,
                               unsigned short* __restrict__ wpk) {
  int idx = blockIdx.x * 256 + threadIdx.x;
  if (idx >= 3 * 16384) return;
  int L = idx >> 14;
  int r = idx & 16383;
  const float* Wl = L == 0 ? Wl1 : (L == 1 ? Wl2 : Wl3);
  const float* Wr = L == 0 ? Wr1 : (L == 1 ? Wr2 : Wr3);
  unsigned short* o = wpk + L * 32768;
  int j = r & 7, l = (r >> 3) & 63, cf = (r >> 9) & 7, ks = r >> 12;
  int k = ks * 32 + (l >> 4) * 8 + j;
  int col = cf * 16 + (l & 15);
  o[r] = f2bf(Wl[k * 128 + col]);
  o[16384 + r] = f2bf(Wr[k * 128 + col]);
}

// Gather-mean: FOUR rows per wave over the COMBINED contiguous edge range
// [b0,b4). Every loop slot is a real edge (no max-degree padding). Row
// selection is by wave-uniform boundary predicates (cndmask, no exec-mask
// divergence, no atomics). 8-edge chunks: 8 uniform EID loads, then 8
// independent coalesced row loads in flight, then predicated accumulate.
// Out-of-range slots clamp to the last edge and match no row (b monotone).
// Lane owns cols 2l,2l+1. fp32 accum, RTN-bf16 row out.
template <bool SRCF32>
__global__ __launch_bounds__(256) void gather_kernel(
    const void* __restrict__ hsrc, const int* __restrict__ OFFS,
    const int* __restrict__ EID, int rowoff,
    unsigned short* __restrict__ meanB, int n) {
  const int wid = blockIdx.x * 4 + (threadIdx.x >> 6);
  const int lane = threadIdx.x & 63;
  const int r0 = wid * 4;
  if (r0 >= n) return;
  const int gr0 = rowoff + r0;

  int b[5];
  b[0] = (gr0 == 0) ? 0 : OFFS[gr0 - 1];
#pragma unroll
  for (int j = 0; j < 4; ++j)
    b[j + 1] = (r0 + j < n) ? OFFS[gr0 + j] : -1;
  // Fix tail rows: empty range == previous boundary.
#pragma unroll
  for (int j = 0; j < 4; ++j)
    if (b[j + 1] < 0) b[j + 1] = b[j];

  float a0[4] = {0.f, 0.f, 0.f, 0.f};
  float a1[4] = {0.f, 0.f, 0.f, 0.f};

  const int bend = b[4];
  if (bend > b[0]) {
    const int blast = bend - 1;
    for (int e = b[0]; e < bend; e += 8) {
      int sid[8];
#pragma unroll
      for (int k = 0; k < 8; ++k) {
        const int ei = e + k;
        sid[k] = EID[ei <= blast ? ei : blast];
      }
      float v0[8], v1[8];
#pragma unroll
      for (int k = 0; k < 8; ++k) {
        if (SRCF32) {
          const float2 v = *(const float2*)((const float*)hsrc +
                                            (size_t)sid[k] * 128 + lane * 2);
          v0[k] = v.x;
          v1[k] = v.y;
        } else {
          const unsigned u = *(const unsigned*)((const unsigned short*)hsrc +
                                                (size_t)sid[k] * 128 + lane * 2);
          v0[k] = ffrom(u << 16);
          v1[k] = ffrom(u & 0xFFFF0000u);
        }
      }
#pragma unroll
      for (int k = 0; k < 8; ++k) {
        const int ei = e + k;
#pragma unroll
        for (int j = 0; j < 4; ++j) {
          const bool p = (ei >= b[j]) & (ei < b[j + 1]);
          a0[j] += p ? v0[k] : 0.f;
          a1[j] += p ? v1[k] : 0.f;
        }
      }
    }
  }

#pragma unroll
  for (int j = 0; j < 4; ++j) {
    const int row = r0 + j;
    if (row < n) {
      const int cnt = b[j + 1] - b[j];
      const float inv = (cnt > 0) ? 1.0f / (float)cnt : 0.0f;
      const unsigned o = (unsigned)f2bf(a0[j] * inv) |
                         ((unsigned)f2bf(a1[j] * inv) << 16);
      *(unsigned*)(meanB + (size_t)row * 128 + lane * 2) = o;
    }
  }
}

// GEMM: 4 waves/block, wave owns 32 rows (2x 16-row tiles).
// Phase 1: issue ALL A-loads (mean bf16 + x) into registers.
// Phase 2: stage the layer's full packed W (64 KB) into LDS (once).
// Phase 3: one barrier; ks/cf loop reads B via conflict-free ds_read_b128,
//          4 MFMA per (ks,cf); no further barriers or global B traffic.
// acc = mean@Wl + x@Wr, +bias, PReLU. Output may alias meanB: every read
// (A hoisted up front) precedes every epilogue store.
template <bool XF32, bool OUTF32>
__global__ __launch_bounds__(256, 2) void gemm_kernel(
    const unsigned short* __restrict__ meanB, const void* __restrict__ xsrc,
    const unsigned short* __restrict__ W,
    const float* __restrict__ bias, const float* __restrict__ alpha,
    void* __restrict__ outp, int n) {
  __shared__ __align__(16) unsigned short wlds[32768];  // 64 KB: full layer W
  const int tid = threadIdx.x;
  const int lane = tid & 63;
  const int wv = tid >> 6;
  const int rbase = blockIdx.x * 128 + wv * 32;
  const int g = lane >> 4;
  const int r16 = lane & 15;

  // Phase 1: all A loads issued first (latency hides under W staging).
  bf16x8 am[2][4], ax[2][4];
  float4 xr[2][4][2];
#pragma unroll
  for (int t = 0; t < 2; ++t) {
    const int row = rbase + t * 16 + r16;
    const bool ok = row < n;
#pragma unroll
    for (int ks = 0; ks < 4; ++ks) {
      if (ok) {
        am[t][ks] = *(const bf16x8*)(meanB + (size_t)row * 128 + ks * 32 + g * 8);
        if (XF32) {
          const float* xp = (const float*)xsrc + (size_t)row * 128 + ks * 32 + g * 8;
          xr[t][ks][0] = *(const float4*)(xp);
          xr[t][ks][1] = *(const float4*)(xp + 4);
        } else {
          ax[t][ks] = *(const bf16x8*)((const unsigned short*)xsrc +
                                       (size_t)row * 128 + ks * 32 + g * 8);
        }
      } else {
        am[t][ks] = (bf16x8)0;
        if (XF32) {
          xr[t][ks][0] = make_float4(0.f, 0.f, 0.f, 0.f);
          xr[t][ks][1] = make_float4(0.f, 0.f, 0.f, 0.f);
        } else {
          ax[t][ks] = (bf16x8)0;
        }
      }
    }
  }

  // Phase 2: stage W -> LDS (4096 float4, 256 threads x 16 iters).
  {
    const float4* Wg = (const float4*)W;
    float4* Ws = (float4*)wlds;
#pragma unroll
    for (int i = 0; i < 16; ++i)
      Ws[i * 256 + tid] = Wg[i * 256 + tid];
  }
  __syncthreads();

  if (XF32) {
#pragma unroll
    for (int t = 0; t < 2; ++t)
#pragma unroll
      for (int ks = 0; ks < 4; ++ks) {
        const float* xv = (const float*)&xr[t][ks][0];
        u32x4 w;
#pragma unroll
        for (int p = 0; p < 4; ++p)
          w[p] = (unsigned)f2bf(xv[2 * p]) | ((unsigned)f2bf(xv[2 * p + 1]) << 16);
        ax[t][ks] = __builtin_bit_cast(bf16x8, w);
      }
  }

  // Phase 3: MFMA loop, B from LDS.
  f32x4 acc[2][8] = {};
#pragma unroll
  for (int ks = 0; ks < 4; ++ks) {
    const unsigned short* wb = wlds + ks * 4096 + lane * 8;
#pragma unroll
    for (int cf = 0; cf < 8; ++cf) {
      const unsigned short* wp = wb + cf * 512;
      bf16x8 wl = *(const bf16x8*)(wp);
      bf16x8 wr = *(const bf16x8*)(wp + 16384);
#pragma unroll
      for (int t = 0; t < 2; ++t) {
        acc[t][cf] = __builtin_amdgcn_mfma_f32_16x16x32_bf16(am[t][ks], wl, acc[t][cf], 0, 0, 0);
        acc[t][cf] = __builtin_amdgcn_mfma_f32_16x16x32_bf16(ax[t][ks], wr, acc[t][cf], 0, 0, 0);
      }
    }
  }

  // Epilogue: C/D layout col = lane&15, row = (lane>>4)*4 + i (verified).
  const int ocol0 = lane & 15;
  const int orow_off = (lane >> 4) * 4;
#pragma unroll
  for (int cf = 0; cf < 8; ++cf) {
    const int ocol = cf * 16 + ocol0;
    const float b = bias[ocol];
    const float a = alpha[ocol];
#pragma unroll
    for (int t = 0; t < 2; ++t) {
      const int orb = rbase + t * 16 + orow_off;
#pragma unroll
      for (int i = 0; i < 4; ++i) {
        const int orow = orb + i;
        if (orow < n) {
          float v = acc[t][cf][i] + b;
          v = v > 0.f ? v : a * v;
          if (OUTF32) {
            ((float*)outp)[(size_t)orow * 128 + ocol] = v;
          } else {
            ((unsigned short*)outp)[(size_t)orow * 128 + ocol] = f2bf(v);
          }
        }
      }
    }
  }
}

extern "C" void kernel_launch(void* const* d_in, const int* in_sizes, int n_in,
                              void* d_out, int out_size, void* d_ws, size_t ws_size,
                              hipStream_t stream) {
  const float* x = (const float*)d_in[0];
  const void* src1 = d_in[1];
  const void* dst1 = d_in[2];
  const void* src2 = d_in[3];
  const void* dst2 = d_in[4];
  const void* src3 = d_in[5];
  const void* dst3 = d_in[6];
  const float* Wl1 = (const float*)d_in[7];
  const float* Wr1 = (const float*)d_in[8];
  const float* b1  = (const float*)d_in[9];
  const float* a1  = (const float*)d_in[10];
  const float* Wl2 = (const float*)d_in[11];
  const float* Wr2 = (const float*)d_in[12];
  const float* b2  = (const float*)d_in[13];
  const float* a2  = (const float*)d_in[14];
  const float* Wl3 = (const float*)d_in[15];
  const float* Wr3 = (const float*)d_in[16];
  const float* b3  = (const float*)d_in[17];
  const float* a3  = (const float*)d_in[18];

  // ws layout: M1 (N1*128 u16), M2 (N2*128 u16), M3 (N3*128 u16),
  //            CNT (cNT i), OFFS (cNT i), EID (cET i), bsum (1024 i),
  //            flag (64 i), wpk (3*32768 u16)
  unsigned short* M1 = (unsigned short*)d_ws;          // mean1 -> h1 (in-place)
  unsigned short* M2 = M1 + (size_t)cN1 * 128;         // mean2 -> h2 (in-place)
  unsigned short* M3 = M2 + (size_t)cN2 * 128;         // mean3
  int* CNT = (int*)(M3 + (size_t)cN3 * 128);
  int* OFFS = CNT + cNT;
  int* EID = OFFS + cNT;
  int* bsum = EID + cET;
  int* flag = bsum + 1024;
  unsigned short* wpk = (unsigned short*)(flag + 64);

  const int nb = NDIV_UP(cNT, 1024);  // 342 <= 512

  detect_idx64_kernel<<<1, 64, 0, stream>>>((const long long*)src1, cE1,
                                            (long long)cN0, flag);
  pack_w3_kernel<<<192, 256, 0, stream>>>(Wl1, Wr1, Wl2, Wr2, Wl3, Wr3, wpk);
  hipMemsetAsync(CNT, 0, (size_t)cNT * sizeof(int), stream);
  hist3_kernel<<<NDIV_UP(cET, 256), 256, 0, stream>>>(dst1, dst2, dst3, flag, CNT);
  scan_reduce<<<nb, 256, 0, stream>>>(CNT, cNT, bsum);
  scan_bsums<<<1, 256, 0, stream>>>(bsum, nb);
  scan_final<<<nb, 256, 0, stream>>>(CNT, cNT, bsum, OFFS);
  fill3_kernel<<<NDIV_UP(cET, 256), 256, 0, stream>>>(src1, dst1, src2, dst2,
                                                      src3, dst3, flag, OFFS, EID);

  // Layer 1: mean(x) -> M1 ; h1 = gemm(M1, x fp32) -> M1 (bf16, in-place)
  gather_kernel<true><<<NDIV_UP(cN1, 16), 256, 0, stream>>>(
      x, OFFS, EID, 0, M1, cN1);
  gemm_kernel<true, false><<<NDIV_UP(cN1, 128), 256, 0, stream>>>(
      M1, x, wpk, b1, a1, M1, cN1);

  // Layer 2: mean(h1) -> M2 ; h2 = gemm(M2, h1 bf16) -> M2 (bf16, in-place)
  gather_kernel<false><<<NDIV_UP(cN2, 16), 256, 0, stream>>>(
      M1, OFFS, EID, cN1, M2, cN2);
  gemm_kernel<false, false><<<NDIV_UP(cN2, 128), 256, 0, stream>>>(
      M2, M1, wpk + 32768, b2, a2, M2, cN2);

  // Layer 3: mean(h2) -> M3 ; out = gemm(M3, h2 bf16) -> d_out (fp32)
  gather_kernel<false><<<NDIV_UP(cN3, 16), 256, 0, stream>>>(
      M2, OFFS, EID, cN1 + cN2, M3, cN3);
  gemm_kernel<false, true><<<NDIV_UP(cN3, 128), 256, 0, stream>>>(
      M3, M2, wpk + 65536, b3, a3, d_out, cN3);
}